// Round 1
// baseline (412.994 us; speedup 1.0000x reference)
//
#include <hip/hip_runtime.h>

// GridManifoldNetwork, round 14 = FULL FUSION. R13 model: hash 3x72.5us at
// the random-64B-line wall with VALU idle (0.78%), dense_mlp 95us with the
// line pipe at only 37% of the wall. Resources were used sequentially ->
// fuse everything into one kernel so hash-gather line traffic and MLP VALU
// overlap: floor = max(58.8M lines / 0.235M lines/us, VALU) ~ 250us.
// Also deletes the feat round-trip (50MB) and 3x redundant x reads (75MB).
//
// Prior falsifications respected: R3/R12 (don't hand-schedule loads; keep
// the R11 straight-line MLP form verbatim), hash merge was hash<->hash
// (same pipe, nothing to overlap) -- this is hash<->VALU fusion.
//
// Risk (falsifiable): fused kernel has 144KB LDS -> 1 block/CU = 16 waves.
// If the line wall is occupancy-sensitive (not a chip-level TCC ceiling),
// fused dur lands >=300us -> next round: partial fusion (L3 only).
//
// Levels: res=16,32,64,128,256,512; F=2; T=2^19; levels 3..5 hashed,
// size 2^19 -> & 0x7FFFF. Entry offsets: 0,4096,36864,299008,823296,1347584.
// Levels 0+1 (entries [0,36864)) staged to LDS as packed bf16x2 (144KB).
// Hash-level features now stay fp32 (no bf16 feat buffer) -> absmax drops.

#define HP1 2654435761u
#define HP2 805459861u
#define HMASK ((1u << 19) - 1u)

typedef float v2f __attribute__((ext_vector_type(2)));

static __device__ __forceinline__ unsigned umin_(unsigned a, unsigned b) {
    return a < b ? a : b;
}

// bf16 round-to-nearest-even pack/unpack.
static __device__ __forceinline__ unsigned f2bf(float f) {
    unsigned u = __float_as_uint(f);
    return (u + 0x7fffu + ((u >> 16) & 1u)) >> 16;
}
static __device__ __forceinline__ float bf2f_lo(unsigned p) {
    return __uint_as_float((p & 0xffffu) << 16);
}
static __device__ __forceinline__ float bf2f_hi(unsigned p) {
    return __uint_as_float(p & 0xffff0000u);
}

static __device__ __forceinline__ v2f vmax0(v2f s) {
#if __has_builtin(__builtin_elementwise_max)
    return __builtin_elementwise_max(s, (v2f)0.0f);
#else
    v2f r; r.x = fmaxf(s.x, 0.0f); r.y = fmaxf(s.y, 0.0f); return r;
#endif
}

// One hashed level for one point (xn in [0,1], scale = res-1):
// 8 divergent 8B gathers + trilerp, fp32 out.
static __device__ __forceinline__ void hash_level_pt(
    const float2* __restrict__ tab, float xn0, float xn1, float xn2,
    float scale, float& o0, float& o1)
{
    const float p0 = fmaf(xn0, scale, 0.5f);
    const float p1 = fmaf(xn1, scale, 0.5f);
    const float p2 = fmaf(xn2, scale, 0.5f);
    const float g0 = floorf(p0), g1 = floorf(p1), g2 = floorf(p2);
    const float f0 = p0 - g0, f1 = p1 - g1, f2 = p2 - g2;
    const unsigned i0 = (unsigned)g0, i1 = (unsigned)g1, i2 = (unsigned)g2;

    const float wx[2] = {1.0f - f0, f0};
    const float wy[2] = {1.0f - f1, f1};
    const float wz[2] = {1.0f - f2, f2};
    const unsigned hx[2] = {i0, i0 + 1u};
    const unsigned hy[2] = {i1 * HP1, (i1 + 1u) * HP1};
    const unsigned hz[2] = {i2 * HP2, (i2 + 1u) * HP2};

    unsigned idx[8];
    float w[8];
    #pragma unroll
    for (int c = 0; c < 8; ++c) {
        const int bx = c & 1, by = (c >> 1) & 1, bz = (c >> 2) & 1;
        idx[c] = (hx[bx] ^ hy[by] ^ hz[bz]) & HMASK;
        w[c] = wx[bx] * wy[by] * wz[bz];
    }
    float2 v[8];
    #pragma unroll
    for (int c = 0; c < 8; ++c) v[c] = tab[idx[c]];

    float a0 = 0.0f, a1 = 0.0f;
    #pragma unroll
    for (int c = 0; c < 8; ++c) {
        a0 = fmaf(w[c], v[c].x, a0);
        a1 = fmaf(w[c], v[c].y, a1);
    }
    o0 = a0;
    o1 = a1;
}

// Prep: pack levels 0+1 to bf16x2 workspace + build transposed wt (1089 f).
__global__ __launch_bounds__(256) void prep_kernel(
    const float2* __restrict__ gtab,
    float* __restrict__ wt, unsigned* __restrict__ packed,
    const float* __restrict__ W0, const float* __restrict__ b0,
    const float* __restrict__ W1, const float* __restrict__ b1)
{
    for (int t = (int)blockIdx.x * 256 + threadIdx.x; t < 36864; t += 64 * 256) {
        const float2 e = gtab[t];
        packed[t] = f2bf(e.x) | (f2bf(e.y) << 16);
    }
    if (blockIdx.x == 0) {
        for (int t = threadIdx.x; t < 1024; t += 256) {
            const int j = t >> 4, i = t & 15;
            wt[t] = (i == 15) ? b0[j] : W0[i * 64 + j];
        }
        if (threadIdx.x < 64) wt[1024 + threadIdx.x] = W1[threadIdx.x];
        if (threadIdx.x == 0) wt[1088] = b1[0];
    }
}

// Dense trilinear level from global fp32 float2 (level 2; R11 form).
static __device__ __forceinline__ void dense_level(
    const float2* __restrict__ tab, unsigned res,
    float xn0, float xn1, float xn2, float& o0, float& o1)
{
    const float scale = (float)(res - 1);
    const float p0 = fmaf(xn0, scale, 0.5f);
    const float p1 = fmaf(xn1, scale, 0.5f);
    const float p2 = fmaf(xn2, scale, 0.5f);
    const float g0 = floorf(p0), g1 = floorf(p1), g2 = floorf(p2);
    const float f0 = p0 - g0, f1 = p1 - g1, f2 = p2 - g2;
    const unsigned i0 = (unsigned)g0, i1 = (unsigned)g1, i2 = (unsigned)g2;

    const unsigned rm1 = res - 1u;
    const unsigned cx[2] = {umin_(i0, rm1), umin_(i0 + 1u, rm1)};
    const unsigned cy[2] = {umin_(i1, rm1) * res, umin_(i1 + 1u, rm1) * res};
    const unsigned cz[2] = {umin_(i2, rm1) * res * res,
                            umin_(i2 + 1u, rm1) * res * res};
    const float wx[2] = {1.0f - f0, f0};
    const float wy[2] = {1.0f - f1, f1};
    const float wz[2] = {1.0f - f2, f2};

    float a0 = 0.0f, a1 = 0.0f;
    #pragma unroll
    for (int c = 0; c < 8; ++c) {
        const int bx = c & 1, by = (c >> 1) & 1, bz = (c >> 2) & 1;
        const unsigned idx = cx[bx] + cy[by] + cz[bz];
        const float w = wx[bx] * wy[by] * wz[bz];
        const float2 v = tab[idx];
        a0 = fmaf(w, v.x, a0);
        a1 = fmaf(w, v.y, a1);
    }
    o0 = a0;
    o1 = a1;
}

// Dense trilinear level from LDS-resident packed bf16x2 table (R11 form).
static __device__ __forceinline__ void dense_level_lds(
    const unsigned* __restrict__ sPk, unsigned off, unsigned res,
    float xn0, float xn1, float xn2, float& o0, float& o1)
{
    const float scale = (float)(res - 1);
    const float p0 = fmaf(xn0, scale, 0.5f);
    const float p1 = fmaf(xn1, scale, 0.5f);
    const float p2 = fmaf(xn2, scale, 0.5f);
    const float g0 = floorf(p0), g1 = floorf(p1), g2 = floorf(p2);
    const float f0 = p0 - g0, f1 = p1 - g1, f2 = p2 - g2;
    const unsigned i0 = (unsigned)g0, i1 = (unsigned)g1, i2 = (unsigned)g2;

    const unsigned rm1 = res - 1u;
    const unsigned cx[2] = {umin_(i0, rm1), umin_(i0 + 1u, rm1)};
    const unsigned cy[2] = {umin_(i1, rm1) * res, umin_(i1 + 1u, rm1) * res};
    const unsigned cz[2] = {umin_(i2, rm1) * res * res,
                            umin_(i2 + 1u, rm1) * res * res};
    const float wx[2] = {1.0f - f0, f0};
    const float wy[2] = {1.0f - f1, f1};
    const float wz[2] = {1.0f - f2, f2};

    float a0 = 0.0f, a1 = 0.0f;
    #pragma unroll
    for (int c = 0; c < 8; ++c) {
        const int bx = c & 1, by = (c >> 1) & 1, bz = (c >> 2) & 1;
        const unsigned p = sPk[off + cx[bx] + cy[by] + cz[bz]];
        const float w = wx[bx] * wy[by] * wz[bz];
        a0 = fmaf(w, bf2f_lo(p), a0);
        a1 = fmaf(w, bf2f_hi(p), a1);
    }
    o0 = a0;
    o1 = a1;
}

// FUSED: hash levels 3/4/5 + dense levels 0/1/2 + MLP, 4 points/thread.
// L1LDS=true: levels 0+1 from 144KB LDS; false: level 0 only (16KB).
// MLP is the R11 form verbatim: weights via SMEM pipe, v_pk_fma over
// 2-point v2f pairs.
template<int BLOCK, bool L1LDS>
__global__ __launch_bounds__(BLOCK, 4) void fused_kernel(
    const float* __restrict__ x,
    const float* __restrict__ grid,
    const float* __restrict__ wt,        // 1089 floats
    const unsigned* __restrict__ packed, // 36864 bf16x2 words (levels 0+1)
    float* __restrict__ out, int N)
{
    extern __shared__ unsigned sPk[];
    const int tid = threadIdx.x;

    const int nstage = L1LDS ? 36864 : 4096;
    for (int t = tid; t < nstage; t += BLOCK)
        sPk[t] = packed[t];
    __syncthreads();

    const int base = blockIdx.x * (BLOCK * 4) + tid;
    const float2* gtab = (const float2*)grid;

    // hp[p][i] = {feature i of point 2p, feature i of point 2p+1}
    v2f hp[2][16];

    #pragma unroll
    for (int k = 0; k < 4; ++k) {
        const int g = base + BLOCK * k;
        const int gs = (g < N) ? g : 0;
        const int p = k >> 1, lane = k & 1;

        const float px = __builtin_nontemporal_load(x + 3 * gs + 0);
        const float py = __builtin_nontemporal_load(x + 3 * gs + 1);
        const float pz = __builtin_nontemporal_load(x + 3 * gs + 2);
        const float xn0 = (px + 1.0f) * 0.5f;
        const float xn1 = (py + 1.0f) * 0.5f;
        const float xn2 = (pz + 1.0f) * 0.5f;

        hp[p][0][lane] = px; hp[p][1][lane] = py; hp[p][2][lane] = pz;
        hp[p][15][lane] = 1.0f;

        // Dense levels 0..2.
        float t3, t4, t5, t6, t7, t8;
        dense_level_lds(sPk, 0u, 16u, xn0, xn1, xn2, t3, t4);
        if (L1LDS)
            dense_level_lds(sPk, 4096u, 32u, xn0, xn1, xn2, t5, t6);
        else
            dense_level(gtab + 4096u, 32u, xn0, xn1, xn2, t5, t6);
        dense_level(gtab + 36864u, 64u, xn0, xn1, xn2, t7, t8);
        hp[p][3][lane] = t3; hp[p][4][lane] = t4;
        hp[p][5][lane] = t5; hp[p][6][lane] = t6;
        hp[p][7][lane] = t7; hp[p][8][lane] = t8;

        // Hashed levels 3..5, inline, fp32 (no feat round-trip).
        float h3a, h3b, h4a, h4b, h5a, h5b;
        hash_level_pt(gtab + 299008u,  xn0, xn1, xn2, 127.0f, h3a, h3b);
        hash_level_pt(gtab + 823296u,  xn0, xn1, xn2, 255.0f, h4a, h4b);
        hash_level_pt(gtab + 1347584u, xn0, xn1, xn2, 511.0f, h5a, h5b);
        hp[p][9][lane]  = h3a; hp[p][10][lane] = h3b;
        hp[p][11][lane] = h4a; hp[p][12][lane] = h4b;
        hp[p][13][lane] = h5a; hp[p][14][lane] = h5b;
    }

    // MLP: out = relu(h @ W0 + b0) @ W1 + b1 (bias folded via h[15]=1).
    const float b1v = wt[1088];
    v2f o2[2];
    o2[0] = (v2f)b1v; o2[1] = (v2f)b1v;

    #pragma unroll 4
    for (int j = 0; j < 64; ++j) {
        float r[16];
        #pragma unroll
        for (int i = 0; i < 16; ++i)
            r[i] = wt[j * 16 + i];          // uniform -> s_load (SMEM pipe)
        const float w1j = wt[1024 + j];
        #pragma unroll
        for (int p = 0; p < 2; ++p) {
            v2f s = (v2f)0.0f;
            #pragma unroll
            for (int i = 0; i < 16; ++i)
                s = hp[p][i] * r[i] + s;     // v_pk_fma_f32
            s = vmax0(s);
            o2[p] = s * w1j + o2[p];
        }
    }

    #pragma unroll
    for (int k = 0; k < 4; ++k) {
        const int g = base + BLOCK * k;
        if (g < N)
            __builtin_nontemporal_store(o2[k >> 1][k & 1], out + g);
    }
}

extern "C" void kernel_launch(void* const* d_in, const int* in_sizes, int n_in,
                              void* d_out, int out_size, void* d_ws, size_t ws_size,
                              hipStream_t stream) {
    const float* x    = (const float*)d_in[0];
    const float* grid = (const float*)d_in[1];
    const float* W0   = (const float*)d_in[2];
    const float* b0   = (const float*)d_in[3];
    const float* W1   = (const float*)d_in[4];
    const float* b1   = (const float*)d_in[5];
    float* out = (float*)d_out;

    const int N = in_sizes[0] / 3;
    const float2* gtab = (const float2*)grid;

    auto align256 = [](size_t v) { return (v + 255) & ~(size_t)255; };
    size_t off = 0;
    const size_t wt_off = off; off += align256(1089 * 4);
    const size_t pk_off = off; off += align256(36864 * 4);
    (void)ws_size;

    float*    wt     = (float*)((char*)d_ws + wt_off);
    unsigned* packed = (unsigned*)((char*)d_ws + pk_off);

    // Prep: pack levels 0+1 + build wt (tiny, ~3us).
    prep_kernel<<<64, 256, 0, stream>>>(gtab, wt, packed, W0, b0, W1, b1);

    // Gate the 144KB-LDS path on what the runtime actually permits
    // (host-side queries: deterministic, graph-capture-safe).
    const size_t bigShm = 36864u * 4u;           // 147456 B
    const void* bigK =
        reinterpret_cast<const void*>(&fused_kernel<1024, true>);
    (void)hipFuncSetAttribute(bigK,
        hipFuncAttributeMaxDynamicSharedMemorySize, (int)bigShm);
    bool big = false;
    hipFuncAttributes fa{};
    if (hipFuncGetAttributes(&fa, bigK) == hipSuccess)
        big = ((size_t)fa.maxDynamicSharedSizeBytes >= bigShm);

    if (big) {
        const int blocksB = (N + 4095) / 4096;   // 1024 thr x 4 pts
        fused_kernel<1024, true><<<blocksB, 1024, bigShm, stream>>>(
            x, (const float*)grid, wt, packed, out, N);
    } else {
        const int blocksF = (N + 1023) / 1024;   // 256 thr x 4 pts
        fused_kernel<256, false><<<blocksF, 256, 4096u * 4u, stream>>>(
            x, (const float*)grid, wt, packed, out, N);
    }
}

// Round 2
// 369.939 us; speedup vs baseline: 1.1164x; 1.1164x over previous
//
#include <hip/hip_runtime.h>

// GridManifoldNetwork, round 15. R14 full fusion FALSIFIED: 14MB gather
// working set vs 4MB/XCD L2 -> FETCH 53MB->964MB, req rate 0.235->0.175M/us,
// 335us. Serial-by-level is L2-optimal (one 4MB table replicated in all 8
// XCD L2s per kernel) -> keep R13 5-kernel structure.
//
// New lever: the wall is REQUEST-count bound (16.8M req / 72.5us = 0.232M/us
// = the measured wall), but unique lines are only ~6/point: x-corner entries
// (i0^m) and ((i0+1)^m) differ by XOR 1 for even i0 -> same aligned 16B pair.
// Hash levels: one dwordx4 pair-load replaces 2 gathers for even i0
// (8 -> 6 req/point avg). Dense level 2: bf16-packed table A + shifted
// duplicate B (clamp baked in) makes EVERY x-pair one aligned 8B load
// (8 -> 4 req/point, table 2MB -> 2x1MB bf16).
//
// Falsifier: if hash dur stays ~72us, wall is unique-line-bound -> revert.
//
// Levels: res=16,32,64,128,256,512; F=2; T=2^19; levels 3..5 hashed,
// & 0x7FFFF. Entry offsets: 0,4096,36864,299008,823296,1347584.
// Levels 0+1 (entries [0,36864)) staged to LDS as packed bf16x2 (144KB).

#define HP1 2654435761u
#define HP2 805459861u
#define HMASK ((1u << 19) - 1u)

typedef float v2f __attribute__((ext_vector_type(2)));

static __device__ __forceinline__ unsigned umin_(unsigned a, unsigned b) {
    return a < b ? a : b;
}

// bf16 round-to-nearest-even pack/unpack.
static __device__ __forceinline__ unsigned f2bf(float f) {
    unsigned u = __float_as_uint(f);
    return (u + 0x7fffu + ((u >> 16) & 1u)) >> 16;
}
static __device__ __forceinline__ float bf2f_lo(unsigned p) {
    return __uint_as_float((p & 0xffffu) << 16);
}
static __device__ __forceinline__ float bf2f_hi(unsigned p) {
    return __uint_as_float(p & 0xffff0000u);
}

static __device__ __forceinline__ v2f vmax0(v2f s) {
#if __has_builtin(__builtin_elementwise_max)
    return __builtin_elementwise_max(s, (v2f)0.0f);
#else
    v2f r; r.x = fmaxf(s.x, 0.0f); r.y = fmaxf(s.y, 0.0f); return r;
#endif
}

// One hashed-level point block, x-pair-coalesced:
// 4 dwordx4 pair-loads always (cover both x-corners when i0 even) +
// 4 extra 8B gathers only when i0 odd. Avg 6 requests/point vs 8.
static __device__ __forceinline__ void hash_body(
    const float* __restrict__ x, const float2* __restrict__ tab,
    unsigned* __restrict__ feat, float scale, int N, int bid)
{
    const int gid = bid * 256 + threadIdx.x;
    if (gid >= N) return;

    const float px = __builtin_nontemporal_load(x + 3 * gid + 0);
    const float py = __builtin_nontemporal_load(x + 3 * gid + 1);
    const float pz = __builtin_nontemporal_load(x + 3 * gid + 2);

    const float p0 = fmaf((px + 1.0f) * 0.5f, scale, 0.5f);
    const float p1 = fmaf((py + 1.0f) * 0.5f, scale, 0.5f);
    const float p2 = fmaf((pz + 1.0f) * 0.5f, scale, 0.5f);
    const float g0 = floorf(p0), g1 = floorf(p1), g2 = floorf(p2);
    const float f0 = p0 - g0, f1 = p1 - g1, f2 = p2 - g2;
    const unsigned i0 = (unsigned)g0, i1 = (unsigned)g1, i2 = (unsigned)g2;

    const float wx[2] = {1.0f - f0, f0};
    const float wy[2] = {1.0f - f1, f1};
    const float wz[2] = {1.0f - f2, f2};
    const unsigned hy[2] = {i1 * HP1, (i1 + 1u) * HP1};
    const unsigned hz[2] = {i2 * HP2, (i2 + 1u) * HP2};

    // v0[c]: x-corner 0, v1[c]: x-corner 1, for (by,bz) = (c&1, c>>1).
    float2 v0[4], v1[4];
    #pragma unroll
    for (int c = 0; c < 4; ++c) {
        const unsigned m = hy[c & 1] ^ hz[(c >> 1) & 1];
        const unsigned e0 = (i0 ^ m) & HMASK;
        // Aligned pair {e0&~1, e0|1}: one 16B load, 16B-aligned.
        const float4 q = *reinterpret_cast<const float4*>(
            reinterpret_cast<const float*>(tab) + 2u * (e0 & ~1u));
        const float2 qlo = make_float2(q.x, q.y);
        const float2 qhi = make_float2(q.z, q.w);
        const bool hi = (e0 & 1u) != 0u;
        v0[c] = hi ? qhi : qlo;
        v1[c] = hi ? qlo : qhi;   // correct iff i0 even (e1 == e0^1)
    }
    if (i0 & 1u) {                // odd i0: x-corner-1 entries not adjacent
        #pragma unroll
        for (int c = 0; c < 4; ++c) {
            const unsigned e1 =
                ((i0 + 1u) ^ hy[c & 1] ^ hz[(c >> 1) & 1]) & HMASK;
            v1[c] = tab[e1];
        }
    }

    float a0 = 0.0f, a1 = 0.0f;
    #pragma unroll
    for (int c = 0; c < 4; ++c) {
        const float wyz = wy[c & 1] * wz[(c >> 1) & 1];
        const float w0 = wyz * wx[0], w1 = wyz * wx[1];
        a0 = fmaf(w0, v0[c].x, a0);
        a1 = fmaf(w0, v0[c].y, a1);
        a0 = fmaf(w1, v1[c].x, a0);
        a1 = fmaf(w1, v1[c].y, a1);
    }
    __builtin_nontemporal_store(f2bf(a0) | (f2bf(a1) << 16), feat + gid);
}

// Hash level 3 + prep folded into 64 tail blocks. Tail now also builds the
// level-2 packed pair tables A2 (identity) and B2 (x-shifted, clamp baked).
__global__ __launch_bounds__(256) void hash3_prep_kernel(
    const float* __restrict__ x, const float2* __restrict__ gtab,
    unsigned* __restrict__ feat0, int N,
    float* __restrict__ wt, unsigned* __restrict__ packed,
    unsigned* __restrict__ A2, unsigned* __restrict__ B2,
    const float* __restrict__ W0, const float* __restrict__ b0,
    const float* __restrict__ W1, const float* __restrict__ b1)
{
    const int nh = (int)gridDim.x - 64;
    if ((int)blockIdx.x >= nh) {
        const int pb = (int)blockIdx.x - nh;   // 0..63
        for (int t = pb * 256 + threadIdx.x; t < 36864; t += 64 * 256) {
            const float2 e = gtab[t];
            packed[t] = f2bf(e.x) | (f2bf(e.y) << 16);
        }
        const float2* g2 = gtab + 36864u;      // level 2, 64^3 entries
        for (int t = pb * 256 + threadIdx.x; t < 262144; t += 64 * 256) {
            const float2 e = g2[t];
            A2[t] = f2bf(e.x) | (f2bf(e.y) << 16);
            const int xc = t & 63;
            const float2 en = g2[(xc == 63) ? t : t + 1];
            B2[t] = f2bf(en.x) | (f2bf(en.y) << 16);
        }
        if (pb == 0) {
            for (int t = threadIdx.x; t < 1024; t += 256) {
                const int j = t >> 4, i = t & 15;
                wt[t] = (i == 15) ? b0[j] : W0[i * 64 + j];
            }
            if (threadIdx.x < 64) wt[1024 + threadIdx.x] = W1[threadIdx.x];
            if (threadIdx.x == 0) wt[1088] = b1[0];
        }
        return;
    }
    hash_body(x, gtab + 299008u, feat0, 127.0f, N, (int)blockIdx.x);
}

__global__ __launch_bounds__(256) void hash_level_kernel(
    const float* __restrict__ x, const float2* __restrict__ tab,
    unsigned* __restrict__ feat, float scale, int N)
{
    hash_body(x, tab, feat, scale, N, (int)blockIdx.x);
}

// Dense trilinear level from global fp32 float2 (level-1 fallback only).
static __device__ __forceinline__ void dense_level(
    const float2* __restrict__ tab, unsigned res,
    float xn0, float xn1, float xn2, float& o0, float& o1)
{
    const float scale = (float)(res - 1);
    const float p0 = fmaf(xn0, scale, 0.5f);
    const float p1 = fmaf(xn1, scale, 0.5f);
    const float p2 = fmaf(xn2, scale, 0.5f);
    const float g0 = floorf(p0), g1 = floorf(p1), g2 = floorf(p2);
    const float f0 = p0 - g0, f1 = p1 - g1, f2 = p2 - g2;
    const unsigned i0 = (unsigned)g0, i1 = (unsigned)g1, i2 = (unsigned)g2;

    const unsigned rm1 = res - 1u;
    const unsigned cx[2] = {umin_(i0, rm1), umin_(i0 + 1u, rm1)};
    const unsigned cy[2] = {umin_(i1, rm1) * res, umin_(i1 + 1u, rm1) * res};
    const unsigned cz[2] = {umin_(i2, rm1) * res * res,
                            umin_(i2 + 1u, rm1) * res * res};
    const float wx[2] = {1.0f - f0, f0};
    const float wy[2] = {1.0f - f1, f1};
    const float wz[2] = {1.0f - f2, f2};

    float a0 = 0.0f, a1 = 0.0f;
    #pragma unroll
    for (int c = 0; c < 8; ++c) {
        const int bx = c & 1, by = (c >> 1) & 1, bz = (c >> 2) & 1;
        const unsigned idx = cx[bx] + cy[by] + cz[bz];
        const float w = wx[bx] * wy[by] * wz[bz];
        const float2 v = tab[idx];
        a0 = fmaf(w, v.x, a0);
        a1 = fmaf(w, v.y, a1);
    }
    o0 = a0;
    o1 = a1;
}

// Dense level 2 (res=64) from packed pair tables: every x-corner pair is
// one aligned 8B load (A2 for even base-x, B2 shifted copy for odd;
// x-clamp at 63 baked into B2). 4 requests/point vs 8.
static __device__ __forceinline__ void dense_level2_pk(
    const unsigned* __restrict__ A2, const unsigned* __restrict__ B2,
    float xn0, float xn1, float xn2, float& o0, float& o1)
{
    const float p0 = fmaf(xn0, 63.0f, 0.5f);
    const float p1 = fmaf(xn1, 63.0f, 0.5f);
    const float p2 = fmaf(xn2, 63.0f, 0.5f);
    const float g0 = floorf(p0), g1 = floorf(p1), g2 = floorf(p2);
    const float f0 = p0 - g0, f1 = p1 - g1, f2 = p2 - g2;
    const unsigned i0 = (unsigned)g0, i1 = (unsigned)g1, i2 = (unsigned)g2;

    const unsigned cx0 = umin_(i0, 63u);
    const unsigned cy[2] = {umin_(i1, 63u) * 64u, umin_(i1 + 1u, 63u) * 64u};
    const unsigned cz[2] = {umin_(i2, 63u) * 4096u,
                            umin_(i2 + 1u, 63u) * 4096u};
    const float wx[2] = {1.0f - f0, f0};
    const float wy[2] = {1.0f - f1, f1};
    const float wz[2] = {1.0f - f2, f2};

    const unsigned* tsel = (cx0 & 1u) ? B2 : A2;
    const unsigned xb = cx0 & ~1u;

    float a0 = 0.0f, a1 = 0.0f;
    #pragma unroll
    for (int c = 0; c < 4; ++c) {
        const int by = c & 1, bz = (c >> 1) & 1;
        const uint2 q = *reinterpret_cast<const uint2*>(
            tsel + xb + cy[by] + cz[bz]);
        const float wyz = wy[by] * wz[bz];
        const float w0 = wyz * wx[0], w1 = wyz * wx[1];
        a0 = fmaf(w0, bf2f_lo(q.x), a0);
        a1 = fmaf(w0, bf2f_hi(q.x), a1);
        a0 = fmaf(w1, bf2f_lo(q.y), a0);
        a1 = fmaf(w1, bf2f_hi(q.y), a1);
    }
    o0 = a0;
    o1 = a1;
}

// Dense trilinear level from LDS-resident packed bf16x2 table (R11 form).
static __device__ __forceinline__ void dense_level_lds(
    const unsigned* __restrict__ sPk, unsigned off, unsigned res,
    float xn0, float xn1, float xn2, float& o0, float& o1)
{
    const float scale = (float)(res - 1);
    const float p0 = fmaf(xn0, scale, 0.5f);
    const float p1 = fmaf(xn1, scale, 0.5f);
    const float p2 = fmaf(xn2, scale, 0.5f);
    const float g0 = floorf(p0), g1 = floorf(p1), g2 = floorf(p2);
    const float f0 = p0 - g0, f1 = p1 - g1, f2 = p2 - g2;
    const unsigned i0 = (unsigned)g0, i1 = (unsigned)g1, i2 = (unsigned)g2;

    const unsigned rm1 = res - 1u;
    const unsigned cx[2] = {umin_(i0, rm1), umin_(i0 + 1u, rm1)};
    const unsigned cy[2] = {umin_(i1, rm1) * res, umin_(i1 + 1u, rm1) * res};
    const unsigned cz[2] = {umin_(i2, rm1) * res * res,
                            umin_(i2 + 1u, rm1) * res * res};
    const float wx[2] = {1.0f - f0, f0};
    const float wy[2] = {1.0f - f1, f1};
    const float wz[2] = {1.0f - f2, f2};

    float a0 = 0.0f, a1 = 0.0f;
    #pragma unroll
    for (int c = 0; c < 8; ++c) {
        const int bx = c & 1, by = (c >> 1) & 1, bz = (c >> 2) & 1;
        const unsigned p = sPk[off + cx[bx] + cy[by] + cz[bz]];
        const float w = wx[bx] * wy[by] * wz[bz];
        a0 = fmaf(w, bf2f_lo(p), a0);
        a1 = fmaf(w, bf2f_hi(p), a1);
    }
    o0 = a0;
    o1 = a1;
}

// Dense levels + MLP, 4 points/thread (R11 form). L1LDS=true: levels 0+1
// from 144KB LDS; false: level 0 only. Level 2 via packed pair tables.
// Weights via SMEM pipe; MLP over 2-pt v2f pairs -> v_pk_fma_f32.
template<int BLOCK, bool L1LDS>
__global__ __launch_bounds__(BLOCK, 4) void dense_mlp_kernel(
    const float* __restrict__ x,
    const float* __restrict__ grid,
    const unsigned* __restrict__ feat,   // [3][N] packed bf16x2
    const float* __restrict__ wt,        // 1089 floats
    const unsigned* __restrict__ packed, // 36864 bf16x2 words (levels 0+1)
    const unsigned* __restrict__ A2,     // level-2 packed (identity)
    const unsigned* __restrict__ B2,     // level-2 packed (x+1, clamped)
    float* __restrict__ out, int N)
{
    extern __shared__ unsigned sPk[];
    const int tid = threadIdx.x;

    const int nstage = L1LDS ? 36864 : 4096;
    for (int t = tid; t < nstage; t += BLOCK)
        sPk[t] = packed[t];
    __syncthreads();

    const int base = blockIdx.x * (BLOCK * 4) + tid;
    const float2* gtab = (const float2*)grid;

    // hp[p][i] = {feature i of point 2p, feature i of point 2p+1}
    v2f hp[2][16];

    #pragma unroll
    for (int k = 0; k < 4; ++k) {
        const int g = base + BLOCK * k;
        const int gs = (g < N) ? g : 0;
        const int p = k >> 1, lane = k & 1;

        const float px = __builtin_nontemporal_load(x + 3 * gs + 0);
        const float py = __builtin_nontemporal_load(x + 3 * gs + 1);
        const float pz = __builtin_nontemporal_load(x + 3 * gs + 2);
        const float xn0 = (px + 1.0f) * 0.5f;
        const float xn1 = (py + 1.0f) * 0.5f;
        const float xn2 = (pz + 1.0f) * 0.5f;

        hp[p][0][lane] = px; hp[p][1][lane] = py; hp[p][2][lane] = pz;
        hp[p][15][lane] = 1.0f;

        float t3, t4, t5, t6, t7, t8;
        dense_level_lds(sPk, 0u, 16u, xn0, xn1, xn2, t3, t4);
        if (L1LDS)
            dense_level_lds(sPk, 4096u, 32u, xn0, xn1, xn2, t5, t6);
        else
            dense_level(gtab + 4096u, 32u, xn0, xn1, xn2, t5, t6);
        dense_level2_pk(A2, B2, xn0, xn1, xn2, t7, t8);
        hp[p][3][lane] = t3; hp[p][4][lane] = t4;
        hp[p][5][lane] = t5; hp[p][6][lane] = t6;
        hp[p][7][lane] = t7; hp[p][8][lane] = t8;

        #pragma unroll
        for (int l = 0; l < 3; ++l) {
            const unsigned pk = __builtin_nontemporal_load(
                feat + (size_t)l * N + gs);
            hp[p][9 + 2 * l][lane]  = bf2f_lo(pk);
            hp[p][10 + 2 * l][lane] = bf2f_hi(pk);
        }
    }

    // MLP: out = relu(h @ W0 + b0) @ W1 + b1 (bias folded via h[15]=1).
    const float b1v = wt[1088];
    v2f o2[2];
    o2[0] = (v2f)b1v; o2[1] = (v2f)b1v;

    #pragma unroll 4
    for (int j = 0; j < 64; ++j) {
        float r[16];
        #pragma unroll
        for (int i = 0; i < 16; ++i)
            r[i] = wt[j * 16 + i];          // uniform -> s_load (SMEM pipe)
        const float w1j = wt[1024 + j];
        #pragma unroll
        for (int p = 0; p < 2; ++p) {
            v2f s = (v2f)0.0f;
            #pragma unroll
            for (int i = 0; i < 16; ++i)
                s = hp[p][i] * r[i] + s;     // v_pk_fma_f32
            s = vmax0(s);
            o2[p] = s * w1j + o2[p];
        }
    }

    #pragma unroll
    for (int k = 0; k < 4; ++k) {
        const int g = base + BLOCK * k;
        if (g < N)
            __builtin_nontemporal_store(o2[k >> 1][k & 1], out + g);
    }
}

extern "C" void kernel_launch(void* const* d_in, const int* in_sizes, int n_in,
                              void* d_out, int out_size, void* d_ws, size_t ws_size,
                              hipStream_t stream) {
    const float* x    = (const float*)d_in[0];
    const float* grid = (const float*)d_in[1];
    const float* W0   = (const float*)d_in[2];
    const float* b0   = (const float*)d_in[3];
    const float* W1   = (const float*)d_in[4];
    const float* b1   = (const float*)d_in[5];
    float* out = (float*)d_out;

    const int N = in_sizes[0] / 3;
    const int blocks1 = (N + 255) / 256;

    const float2* gtab = (const float2*)grid;

    auto align256 = [](size_t v) { return (v + 255) & ~(size_t)255; };
    size_t off = 0;
    const size_t feat_off = off; off += align256((size_t)3 * N * 4);
    const size_t wt_off   = off; off += align256(1089 * 4);
    const size_t pk_off   = off; off += align256(36864 * 4);
    const size_t a2_off   = off; off += align256(262144 * 4);
    const size_t b2_off   = off; off += align256(262144 * 4);
    (void)ws_size;

    unsigned* feat   = (unsigned*)((char*)d_ws + feat_off);
    float*    wt     = (float*)((char*)d_ws + wt_off);
    unsigned* packed = (unsigned*)((char*)d_ws + pk_off);
    unsigned* A2     = (unsigned*)((char*)d_ws + a2_off);
    unsigned* B2     = (unsigned*)((char*)d_ws + b2_off);

    // Hash level 3 + prep (64 tail blocks: packed levels 0+1, A2/B2, wt).
    hash3_prep_kernel<<<blocks1 + 64, 256, 0, stream>>>(
        x, gtab, feat + (size_t)0 * N, N, wt, packed, A2, B2, W0, b0, W1, b1);
    hash_level_kernel<<<blocks1, 256, 0, stream>>>(x, gtab + 823296u,
                                                   feat + (size_t)1 * N, 255.0f, N);
    hash_level_kernel<<<blocks1, 256, 0, stream>>>(x, gtab + 1347584u,
                                                   feat + (size_t)2 * N, 511.0f, N);

    // Gate the 144KB-LDS path on what the runtime actually permits
    // (host-side queries: deterministic, graph-capture-safe).
    const size_t bigShm = 36864u * 4u;           // 147456 B
    const void* bigK =
        reinterpret_cast<const void*>(&dense_mlp_kernel<1024, true>);
    (void)hipFuncSetAttribute(bigK,
        hipFuncAttributeMaxDynamicSharedMemorySize, (int)bigShm);
    bool big = false;
    hipFuncAttributes fa{};
    if (hipFuncGetAttributes(&fa, bigK) == hipSuccess)
        big = ((size_t)fa.maxDynamicSharedSizeBytes >= bigShm);

    if (big) {
        const int blocksB = (N + 4095) / 4096;   // 1024 thr x 4 pts
        dense_mlp_kernel<1024, true><<<blocksB, 1024, bigShm, stream>>>(
            x, (const float*)grid, feat, wt, packed, A2, B2, out, N);
    } else {
        const int blocksF = (N + 1023) / 1024;   // 256 thr x 4 pts
        dense_mlp_kernel<256, false><<<blocksF, 256, 4096u * 4u, stream>>>(
            x, (const float*)grid, feat, wt, packed, A2, B2, out, N);
    }
}

// Round 3
// 315.425 us; speedup vs baseline: 1.3093x; 1.1728x over previous
//
#include <hip/hip_runtime.h>

// GridManifoldNetwork, round 16. R15 post-mortem nailed the wall model:
// hash dur went 72.5->90.6us when requested bytes went 64->80 B/pt while
// request count FELL (8->6) and unique lines stayed ~6. Only the
// REQUESTED-BYTES model (cost ~ bytes through the gather return path,
// ~1.85 TB/s per kernel; 16B req = 2x 8B req) predicts 90.6 exactly.
// -> Invert strategy: don't coalesce requests, SHRINK ENTRIES.
//
// R16: bf16-pack hash tables 3/4/5 (standalone prep kernel, levels are
// contiguous: offsets 299008..1871872). Gathers become 4B dwords:
// 64 -> 32 B/pt. Tables shrink 4MB -> 2MB each = per-XCD-L2-resident with
// slack (R13's 4MB exactly filled L2; streams evicted it). Hash gathers
// revert to the proven plain 8-gather R13 form (pair-loads falsified).
// Keep R15's A2/B2 bf16 level-2 pair tables (dense_mlp 95->91, verified).
//
// Precision precedent: dense levels 0/1/2 already lerp from bf16 entries;
// absmax pinned at 0.00390625 across R13/R14/R15 (not feature-bound).
//
// Predicted: hash 72.5 -> ~36-45us each (FETCH per hash dispatch drops
// hard if 2MB L2 residency kicks in); total ~225-245us.
//
// Levels: res=16,32,64,128,256,512; F=2; T=2^19; levels 3..5 hashed,
// & 0x7FFFF. Entry offsets: 0,4096,36864,299008,823296,1347584.
// Levels 0+1 (entries [0,36864)) staged to LDS as packed bf16x2 (144KB).

#define HP1 2654435761u
#define HP2 805459861u
#define HMASK ((1u << 19) - 1u)

typedef float v2f __attribute__((ext_vector_type(2)));

static __device__ __forceinline__ unsigned umin_(unsigned a, unsigned b) {
    return a < b ? a : b;
}

// bf16 round-to-nearest-even pack/unpack.
static __device__ __forceinline__ unsigned f2bf(float f) {
    unsigned u = __float_as_uint(f);
    return (u + 0x7fffu + ((u >> 16) & 1u)) >> 16;
}
static __device__ __forceinline__ float bf2f_lo(unsigned p) {
    return __uint_as_float((p & 0xffffu) << 16);
}
static __device__ __forceinline__ float bf2f_hi(unsigned p) {
    return __uint_as_float(p & 0xffff0000u);
}

static __device__ __forceinline__ v2f vmax0(v2f s) {
#if __has_builtin(__builtin_elementwise_max)
    return __builtin_elementwise_max(s, (v2f)0.0f);
#else
    v2f r; r.x = fmaxf(s.x, 0.0f); r.y = fmaxf(s.y, 0.0f); return r;
#endif
}

// Prep: pack levels 0+1 (LDS staging source), level-2 pair tables A2/B2,
// and hash tables 3..5 (contiguous 1572864 entries) to bf16x2. Build wt.
__global__ __launch_bounds__(256) void prep_kernel(
    const float2* __restrict__ gtab,
    float* __restrict__ wt, unsigned* __restrict__ packed,
    unsigned* __restrict__ A2, unsigned* __restrict__ B2,
    unsigned* __restrict__ pk345,
    const float* __restrict__ W0, const float* __restrict__ b0,
    const float* __restrict__ W1, const float* __restrict__ b1)
{
    const int stride = (int)gridDim.x * 256;
    const int t0 = (int)blockIdx.x * 256 + threadIdx.x;

    for (int t = t0; t < 36864; t += stride) {
        const float2 e = gtab[t];
        packed[t] = f2bf(e.x) | (f2bf(e.y) << 16);
    }
    const float2* g2 = gtab + 36864u;          // level 2, 64^3 entries
    for (int t = t0; t < 262144; t += stride) {
        const float2 e = g2[t];
        A2[t] = f2bf(e.x) | (f2bf(e.y) << 16);
        const int xc = t & 63;
        const float2 en = g2[(xc == 63) ? t : t + 1];
        B2[t] = f2bf(en.x) | (f2bf(en.y) << 16);
    }
    const float2* gh = gtab + 299008u;         // levels 3..5, contiguous
    for (int t = t0; t < 3 * 524288; t += stride) {
        const float2 e = gh[t];
        pk345[t] = f2bf(e.x) | (f2bf(e.y) << 16);
    }
    if (blockIdx.x == 0) {
        for (int t = threadIdx.x; t < 1024; t += 256) {
            const int j = t >> 4, i = t & 15;
            wt[t] = (i == 15) ? b0[j] : W0[i * 64 + j];
        }
        if (threadIdx.x < 64) wt[1024 + threadIdx.x] = W1[threadIdx.x];
        if (threadIdx.x == 0) wt[1088] = b1[0];
    }
}

// One hashed level, R13 plain-8-gather form, bf16x2-packed table:
// 8 divergent 4B gathers (32 B/pt random) + trilerp + bf16 pack.
__global__ __launch_bounds__(256) void hash_level_kernel(
    const float* __restrict__ x, const unsigned* __restrict__ tab,
    unsigned* __restrict__ feat, float scale, int N)
{
    const int gid = (int)blockIdx.x * 256 + threadIdx.x;
    if (gid >= N) return;

    const float px = __builtin_nontemporal_load(x + 3 * gid + 0);
    const float py = __builtin_nontemporal_load(x + 3 * gid + 1);
    const float pz = __builtin_nontemporal_load(x + 3 * gid + 2);

    const float p0 = fmaf((px + 1.0f) * 0.5f, scale, 0.5f);
    const float p1 = fmaf((py + 1.0f) * 0.5f, scale, 0.5f);
    const float p2 = fmaf((pz + 1.0f) * 0.5f, scale, 0.5f);
    const float g0 = floorf(p0), g1 = floorf(p1), g2 = floorf(p2);
    const float f0 = p0 - g0, f1 = p1 - g1, f2 = p2 - g2;
    const unsigned i0 = (unsigned)g0, i1 = (unsigned)g1, i2 = (unsigned)g2;

    const float wx[2] = {1.0f - f0, f0};
    const float wy[2] = {1.0f - f1, f1};
    const float wz[2] = {1.0f - f2, f2};
    const unsigned hx[2] = {i0, i0 + 1u};
    const unsigned hy[2] = {i1 * HP1, (i1 + 1u) * HP1};
    const unsigned hz[2] = {i2 * HP2, (i2 + 1u) * HP2};

    unsigned idx[8];
    float w[8];
    #pragma unroll
    for (int c = 0; c < 8; ++c) {
        const int bx = c & 1, by = (c >> 1) & 1, bz = (c >> 2) & 1;
        idx[c] = (hx[bx] ^ hy[by] ^ hz[bz]) & HMASK;
        w[c] = wx[bx] * wy[by] * wz[bz];
    }
    unsigned v[8];
    #pragma unroll
    for (int c = 0; c < 8; ++c) v[c] = tab[idx[c]];

    float a0 = 0.0f, a1 = 0.0f;
    #pragma unroll
    for (int c = 0; c < 8; ++c) {
        a0 = fmaf(w[c], bf2f_lo(v[c]), a0);
        a1 = fmaf(w[c], bf2f_hi(v[c]), a1);
    }
    __builtin_nontemporal_store(f2bf(a0) | (f2bf(a1) << 16), feat + gid);
}

// Dense trilinear level from global fp32 float2 (level-1 fallback only).
static __device__ __forceinline__ void dense_level(
    const float2* __restrict__ tab, unsigned res,
    float xn0, float xn1, float xn2, float& o0, float& o1)
{
    const float scale = (float)(res - 1);
    const float p0 = fmaf(xn0, scale, 0.5f);
    const float p1 = fmaf(xn1, scale, 0.5f);
    const float p2 = fmaf(xn2, scale, 0.5f);
    const float g0 = floorf(p0), g1 = floorf(p1), g2 = floorf(p2);
    const float f0 = p0 - g0, f1 = p1 - g1, f2 = p2 - g2;
    const unsigned i0 = (unsigned)g0, i1 = (unsigned)g1, i2 = (unsigned)g2;

    const unsigned rm1 = res - 1u;
    const unsigned cx[2] = {umin_(i0, rm1), umin_(i0 + 1u, rm1)};
    const unsigned cy[2] = {umin_(i1, rm1) * res, umin_(i1 + 1u, rm1) * res};
    const unsigned cz[2] = {umin_(i2, rm1) * res * res,
                            umin_(i2 + 1u, rm1) * res * res};
    const float wx[2] = {1.0f - f0, f0};
    const float wy[2] = {1.0f - f1, f1};
    const float wz[2] = {1.0f - f2, f2};

    float a0 = 0.0f, a1 = 0.0f;
    #pragma unroll
    for (int c = 0; c < 8; ++c) {
        const int bx = c & 1, by = (c >> 1) & 1, bz = (c >> 2) & 1;
        const unsigned idx = cx[bx] + cy[by] + cz[bz];
        const float w = wx[bx] * wy[by] * wz[bz];
        const float2 v = tab[idx];
        a0 = fmaf(w, v.x, a0);
        a1 = fmaf(w, v.y, a1);
    }
    o0 = a0;
    o1 = a1;
}

// Dense level 2 (res=64) from packed pair tables: every x-corner pair is
// one aligned 8B load (A2 even base-x, B2 shifted copy for odd; clamp
// baked into B2). 4 requests x 8B = 32 B/pt.
static __device__ __forceinline__ void dense_level2_pk(
    const unsigned* __restrict__ A2, const unsigned* __restrict__ B2,
    float xn0, float xn1, float xn2, float& o0, float& o1)
{
    const float p0 = fmaf(xn0, 63.0f, 0.5f);
    const float p1 = fmaf(xn1, 63.0f, 0.5f);
    const float p2 = fmaf(xn2, 63.0f, 0.5f);
    const float g0 = floorf(p0), g1 = floorf(p1), g2 = floorf(p2);
    const float f0 = p0 - g0, f1 = p1 - g1, f2 = p2 - g2;
    const unsigned i0 = (unsigned)g0, i1 = (unsigned)g1, i2 = (unsigned)g2;

    const unsigned cx0 = umin_(i0, 63u);
    const unsigned cy[2] = {umin_(i1, 63u) * 64u, umin_(i1 + 1u, 63u) * 64u};
    const unsigned cz[2] = {umin_(i2, 63u) * 4096u,
                            umin_(i2 + 1u, 63u) * 4096u};
    const float wx[2] = {1.0f - f0, f0};
    const float wy[2] = {1.0f - f1, f1};
    const float wz[2] = {1.0f - f2, f2};

    const unsigned* tsel = (cx0 & 1u) ? B2 : A2;
    const unsigned xb = cx0 & ~1u;

    float a0 = 0.0f, a1 = 0.0f;
    #pragma unroll
    for (int c = 0; c < 4; ++c) {
        const int by = c & 1, bz = (c >> 1) & 1;
        const uint2 q = *reinterpret_cast<const uint2*>(
            tsel + xb + cy[by] + cz[bz]);
        const float wyz = wy[by] * wz[bz];
        const float w0 = wyz * wx[0], w1 = wyz * wx[1];
        a0 = fmaf(w0, bf2f_lo(q.x), a0);
        a1 = fmaf(w0, bf2f_hi(q.x), a1);
        a0 = fmaf(w1, bf2f_lo(q.y), a0);
        a1 = fmaf(w1, bf2f_hi(q.y), a1);
    }
    o0 = a0;
    o1 = a1;
}

// Dense trilinear level from LDS-resident packed bf16x2 table (R11 form).
static __device__ __forceinline__ void dense_level_lds(
    const unsigned* __restrict__ sPk, unsigned off, unsigned res,
    float xn0, float xn1, float xn2, float& o0, float& o1)
{
    const float scale = (float)(res - 1);
    const float p0 = fmaf(xn0, scale, 0.5f);
    const float p1 = fmaf(xn1, scale, 0.5f);
    const float p2 = fmaf(xn2, scale, 0.5f);
    const float g0 = floorf(p0), g1 = floorf(p1), g2 = floorf(p2);
    const float f0 = p0 - g0, f1 = p1 - g1, f2 = p2 - g2;
    const unsigned i0 = (unsigned)g0, i1 = (unsigned)g1, i2 = (unsigned)g2;

    const unsigned rm1 = res - 1u;
    const unsigned cx[2] = {umin_(i0, rm1), umin_(i0 + 1u, rm1)};
    const unsigned cy[2] = {umin_(i1, rm1) * res, umin_(i1 + 1u, rm1) * res};
    const unsigned cz[2] = {umin_(i2, rm1) * res * res,
                            umin_(i2 + 1u, rm1) * res * res};
    const float wx[2] = {1.0f - f0, f0};
    const float wy[2] = {1.0f - f1, f1};
    const float wz[2] = {1.0f - f2, f2};

    float a0 = 0.0f, a1 = 0.0f;
    #pragma unroll
    for (int c = 0; c < 8; ++c) {
        const int bx = c & 1, by = (c >> 1) & 1, bz = (c >> 2) & 1;
        const unsigned p = sPk[off + cx[bx] + cy[by] + cz[bz]];
        const float w = wx[bx] * wy[by] * wz[bz];
        a0 = fmaf(w, bf2f_lo(p), a0);
        a1 = fmaf(w, bf2f_hi(p), a1);
    }
    o0 = a0;
    o1 = a1;
}

// Dense levels + MLP, 4 points/thread (R11 form). L1LDS=true: levels 0+1
// from 144KB LDS; false: level 0 only. Level 2 via packed pair tables.
// Weights via SMEM pipe; MLP over 2-pt v2f pairs -> v_pk_fma_f32.
template<int BLOCK, bool L1LDS>
__global__ __launch_bounds__(BLOCK, 4) void dense_mlp_kernel(
    const float* __restrict__ x,
    const float* __restrict__ grid,
    const unsigned* __restrict__ feat,   // [3][N] packed bf16x2
    const float* __restrict__ wt,        // 1089 floats
    const unsigned* __restrict__ packed, // 36864 bf16x2 words (levels 0+1)
    const unsigned* __restrict__ A2,     // level-2 packed (identity)
    const unsigned* __restrict__ B2,     // level-2 packed (x+1, clamped)
    float* __restrict__ out, int N)
{
    extern __shared__ unsigned sPk[];
    const int tid = threadIdx.x;

    const int nstage = L1LDS ? 36864 : 4096;
    for (int t = tid; t < nstage; t += BLOCK)
        sPk[t] = packed[t];
    __syncthreads();

    const int base = blockIdx.x * (BLOCK * 4) + tid;
    const float2* gtab = (const float2*)grid;

    // hp[p][i] = {feature i of point 2p, feature i of point 2p+1}
    v2f hp[2][16];

    #pragma unroll
    for (int k = 0; k < 4; ++k) {
        const int g = base + BLOCK * k;
        const int gs = (g < N) ? g : 0;
        const int p = k >> 1, lane = k & 1;

        const float px = __builtin_nontemporal_load(x + 3 * gs + 0);
        const float py = __builtin_nontemporal_load(x + 3 * gs + 1);
        const float pz = __builtin_nontemporal_load(x + 3 * gs + 2);
        const float xn0 = (px + 1.0f) * 0.5f;
        const float xn1 = (py + 1.0f) * 0.5f;
        const float xn2 = (pz + 1.0f) * 0.5f;

        hp[p][0][lane] = px; hp[p][1][lane] = py; hp[p][2][lane] = pz;
        hp[p][15][lane] = 1.0f;

        float t3, t4, t5, t6, t7, t8;
        dense_level_lds(sPk, 0u, 16u, xn0, xn1, xn2, t3, t4);
        if (L1LDS)
            dense_level_lds(sPk, 4096u, 32u, xn0, xn1, xn2, t5, t6);
        else
            dense_level(gtab + 4096u, 32u, xn0, xn1, xn2, t5, t6);
        dense_level2_pk(A2, B2, xn0, xn1, xn2, t7, t8);
        hp[p][3][lane] = t3; hp[p][4][lane] = t4;
        hp[p][5][lane] = t5; hp[p][6][lane] = t6;
        hp[p][7][lane] = t7; hp[p][8][lane] = t8;

        #pragma unroll
        for (int l = 0; l < 3; ++l) {
            const unsigned pk = __builtin_nontemporal_load(
                feat + (size_t)l * N + gs);
            hp[p][9 + 2 * l][lane]  = bf2f_lo(pk);
            hp[p][10 + 2 * l][lane] = bf2f_hi(pk);
        }
    }

    // MLP: out = relu(h @ W0 + b0) @ W1 + b1 (bias folded via h[15]=1).
    const float b1v = wt[1088];
    v2f o2[2];
    o2[0] = (v2f)b1v; o2[1] = (v2f)b1v;

    #pragma unroll 4
    for (int j = 0; j < 64; ++j) {
        float r[16];
        #pragma unroll
        for (int i = 0; i < 16; ++i)
            r[i] = wt[j * 16 + i];          // uniform -> s_load (SMEM pipe)
        const float w1j = wt[1024 + j];
        #pragma unroll
        for (int p = 0; p < 2; ++p) {
            v2f s = (v2f)0.0f;
            #pragma unroll
            for (int i = 0; i < 16; ++i)
                s = hp[p][i] * r[i] + s;     // v_pk_fma_f32
            s = vmax0(s);
            o2[p] = s * w1j + o2[p];
        }
    }

    #pragma unroll
    for (int k = 0; k < 4; ++k) {
        const int g = base + BLOCK * k;
        if (g < N)
            __builtin_nontemporal_store(o2[k >> 1][k & 1], out + g);
    }
}

extern "C" void kernel_launch(void* const* d_in, const int* in_sizes, int n_in,
                              void* d_out, int out_size, void* d_ws, size_t ws_size,
                              hipStream_t stream) {
    const float* x    = (const float*)d_in[0];
    const float* grid = (const float*)d_in[1];
    const float* W0   = (const float*)d_in[2];
    const float* b0   = (const float*)d_in[3];
    const float* W1   = (const float*)d_in[4];
    const float* b1   = (const float*)d_in[5];
    float* out = (float*)d_out;

    const int N = in_sizes[0] / 3;
    const int blocks1 = (N + 255) / 256;

    const float2* gtab = (const float2*)grid;

    auto align256 = [](size_t v) { return (v + 255) & ~(size_t)255; };
    size_t off = 0;
    const size_t feat_off = off; off += align256((size_t)3 * N * 4);
    const size_t wt_off   = off; off += align256(1089 * 4);
    const size_t pk_off   = off; off += align256(36864 * 4);
    const size_t a2_off   = off; off += align256(262144 * 4);
    const size_t b2_off   = off; off += align256(262144 * 4);
    const size_t h_off    = off; off += align256((size_t)3 * 524288 * 4);
    (void)ws_size;

    unsigned* feat   = (unsigned*)((char*)d_ws + feat_off);
    float*    wt     = (float*)((char*)d_ws + wt_off);
    unsigned* packed = (unsigned*)((char*)d_ws + pk_off);
    unsigned* A2     = (unsigned*)((char*)d_ws + a2_off);
    unsigned* B2     = (unsigned*)((char*)d_ws + b2_off);
    unsigned* pk345  = (unsigned*)((char*)d_ws + h_off);

    // Prep: pack all tables to bf16x2 + build wt (~6us, bandwidth-bound).
    prep_kernel<<<512, 256, 0, stream>>>(gtab, wt, packed, A2, B2, pk345,
                                         W0, b0, W1, b1);

    // Hash levels 3..5 from 2MB bf16 tables (4B gathers, 32 B/pt random).
    hash_level_kernel<<<blocks1, 256, 0, stream>>>(
        x, pk345 + (size_t)0 * 524288, feat + (size_t)0 * N, 127.0f, N);
    hash_level_kernel<<<blocks1, 256, 0, stream>>>(
        x, pk345 + (size_t)1 * 524288, feat + (size_t)1 * N, 255.0f, N);
    hash_level_kernel<<<blocks1, 256, 0, stream>>>(
        x, pk345 + (size_t)2 * 524288, feat + (size_t)2 * N, 511.0f, N);

    // Gate the 144KB-LDS path on what the runtime actually permits
    // (host-side queries: deterministic, graph-capture-safe).
    const size_t bigShm = 36864u * 4u;           // 147456 B
    const void* bigK =
        reinterpret_cast<const void*>(&dense_mlp_kernel<1024, true>);
    (void)hipFuncSetAttribute(bigK,
        hipFuncAttributeMaxDynamicSharedMemorySize, (int)bigShm);
    bool big = false;
    hipFuncAttributes fa{};
    if (hipFuncGetAttributes(&fa, bigK) == hipSuccess)
        big = ((size_t)fa.maxDynamicSharedSizeBytes >= bigShm);

    if (big) {
        const int blocksB = (N + 4095) / 4096;   // 1024 thr x 4 pts
        dense_mlp_kernel<1024, true><<<blocksB, 1024, bigShm, stream>>>(
            x, (const float*)grid, feat, wt, packed, A2, B2, out, N);
    } else {
        const int blocksF = (N + 1023) / 1024;   // 256 thr x 4 pts
        dense_mlp_kernel<256, false><<<blocksF, 256, 4096u * 4u, stream>>>(
            x, (const float*)grid, feat, wt, packed, A2, B2, out, N);
    }
}